// Round 4
// baseline (505.469 us; speedup 1.0000x reference)
//
#include <hip/hip_runtime.h>
#include <hip/hip_bf16.h>
#include <stdint.h>

// ---------------- helpers ----------------
__device__ __forceinline__ float bf2f(unsigned short u) {
    unsigned int x = ((unsigned int)u) << 16;
    return __uint_as_float(x);
}
__device__ __forceinline__ unsigned short f2bf(float f) {
    unsigned int x = __float_as_uint(f);
    unsigned int lsb = (x >> 16) & 1u;
    x += 0x7fffu + lsb;           // round-to-nearest-even
    return (unsigned short)(x >> 16);
}
__device__ __forceinline__ float loadF(const void* p, int i, int isbf) {
    return isbf ? bf2f(((const unsigned short*)p)[i]) : ((const float*)p)[i];
}

// ---------------- dtype detection (64-lane parallel) ----------------
// flags[0] = floats are bf16 (1) or f32 (0)
// flags[1] = edge_index is int64 (1) or int32 (0)
__global__ void k_detect(const void* x, const void* eidx, int* flags) {
    int l = threadIdx.x;   // 64 threads
    const unsigned short* u = (const unsigned short*)x;
    float a = fabsf(bf2f(u[2 * l]));
    bool ok = (a == 0.0f) || (a > 1e-30f && a < 1e4f);
    unsigned long long mbf = __ballot(ok);
    const int* ip = (const int*)eidx;
    unsigned long long mi64 = __ballot(ip[2 * l + 1] == 0);
    if (l == 0) {
        flags[0] = (mbf  == ~0ULL) ? 1 : 0;
        flags[1] = (mi64 == ~0ULL) ? 1 : 0;
    }
}

// ---------------- edge binning by dst range (replaces CSR) ----------------
// Buckets of R = 1<<rsh nodes. Per-block LDS histogram -> one global atomic
// per (block,bucket) -> contiguous segment writes (coalesced-ish).
__global__ void k_bin(const void* eidx, int E, int rsh, int B, int cap,
                      int2* bins, int* bcnt, const int* flags) {
    extern __shared__ int sh[];            // 2*B ints
    int* hist  = sh;
    int* base_s = sh + B;
    const int i64 = flags[1];
    const int t = threadIdx.x, nt = blockDim.x;
    const long long i0 = (long long)blockIdx.x * E / gridDim.x;
    const long long i1 = (long long)(blockIdx.x + 1) * E / gridDim.x;
    const long long* e64 = (const long long*)eidx;
    const int* e32 = (const int*)eidx;

    for (int b = t; b < B; b += nt) hist[b] = 0;
    __syncthreads();
    // pass 1: count
    for (long long i = i0 + t; i < i1; i += nt) {
        int d = i64 ? (int)e64[E + i] : e32[E + i];
        atomicAdd(&hist[d >> rsh], 1);
    }
    __syncthreads();
    // reserve segments
    for (int b = t; b < B; b += nt) {
        int c = hist[b];
        base_s[b] = c ? atomicAdd(&bcnt[b], c) : 0;
        hist[b] = 0;
    }
    __syncthreads();
    // pass 2: scatter (re-reads are L2-hot)
    for (long long i = i0 + t; i < i1; i += nt) {
        int d, s;
        if (i64) { d = (int)e64[E + i]; s = (int)e64[i]; }
        else     { d = e32[E + i];     s = e32[i]; }
        int b = d >> rsh;
        int pos = base_s[b] + atomicAdd(&hist[b], 1);
        if (pos >= cap) pos = cap - 1;     // paranoia guard
        bins[(size_t)b * cap + pos] = make_int2(s, d);
    }
}

// ---------------- per-bucket degree histogram -> dinv ----------------
__global__ void k_bdeg(const int2* bins, const int* bcnt, int cap, int rsh,
                       int n, float* dinv) {
    extern __shared__ int dh[];            // R ints
    const int R = 1 << rsh;
    const int b = blockIdx.x, t = threadIdx.x, nt = blockDim.x;
    for (int r = t; r < R; r += nt) dh[r] = 0;
    __syncthreads();
    int cnt = bcnt[b]; if (cnt > cap) cnt = cap;
    const int2* eb = bins + (size_t)b * cap;
    for (int e = t; e < cnt; e += nt)
        atomicAdd(&dh[eb[e].y & (R - 1)], 1);
    __syncthreads();
    const int v0 = b << rsh;
    for (int r = t; r < R; r += nt) {
        int v = v0 + r;
        if (v < n) dinv[v] = rsqrtf((float)(dh[r] + 1));   // +1 self loop
    }
}

// ---------------- consts: M = W1^3 W2 ; cvecs = {g3,g2,g1,b2} ----------------
#define TS 68
__global__ void k_consts(const void* W1, const void* b1, const void* W2, const void* b2,
                         float* M, float* cvecs, const int* flags) {
    __shared__ float A[64 * 64];
    __shared__ float T1[64 * TS];
    __shared__ float T2[64 * TS];
    __shared__ float B2[64 * 16];
    __shared__ float bv[64], bw1[64], bw2[64];
    int bf = flags[0];
    int t = threadIdx.x;   // 256 threads
    for (int i = t; i < 4096; i += 256) A[i] = loadF(W1, i, bf);
    for (int i = t; i < 1024; i += 256) B2[i] = loadF(W2, i, bf);
    if (t < 64) bv[t] = loadF(b1, t, bf);
    __syncthreads();

    const int i0 = (t >> 4) * 4;
    const int j0 = (t & 15) * 4;
    {   // T1 = A @ A
        float acc[4][4] = {};
#pragma unroll 8
        for (int k = 0; k < 64; ++k) {
            float a0 = A[(i0 + 0) * 64 + k];
            float a1 = A[(i0 + 1) * 64 + k];
            float a2 = A[(i0 + 2) * 64 + k];
            float a3 = A[(i0 + 3) * 64 + k];
            float4 bq = *(const float4*)&A[k * 64 + j0];
            acc[0][0] += a0 * bq.x; acc[0][1] += a0 * bq.y; acc[0][2] += a0 * bq.z; acc[0][3] += a0 * bq.w;
            acc[1][0] += a1 * bq.x; acc[1][1] += a1 * bq.y; acc[1][2] += a1 * bq.z; acc[1][3] += a1 * bq.w;
            acc[2][0] += a2 * bq.x; acc[2][1] += a2 * bq.y; acc[2][2] += a2 * bq.z; acc[2][3] += a2 * bq.w;
            acc[3][0] += a3 * bq.x; acc[3][1] += a3 * bq.y; acc[3][2] += a3 * bq.z; acc[3][3] += a3 * bq.w;
        }
#pragma unroll
        for (int ii = 0; ii < 4; ++ii)
            *(float4*)&T1[(i0 + ii) * TS + j0] = make_float4(acc[ii][0], acc[ii][1], acc[ii][2], acc[ii][3]);
    }
    if (t < 64) {
        float acc = 0.f;
#pragma unroll 8
        for (int i = 0; i < 64; ++i) acc += bv[i] * A[i * 64 + t];
        bw1[t] = acc;
    }
    __syncthreads();
    {   // T2 = T1 @ A
        float acc[4][4] = {};
#pragma unroll 8
        for (int k = 0; k < 64; ++k) {
            float a0 = T1[(i0 + 0) * TS + k];
            float a1 = T1[(i0 + 1) * TS + k];
            float a2 = T1[(i0 + 2) * TS + k];
            float a3 = T1[(i0 + 3) * TS + k];
            float4 bq = *(const float4*)&A[k * 64 + j0];
            acc[0][0] += a0 * bq.x; acc[0][1] += a0 * bq.y; acc[0][2] += a0 * bq.z; acc[0][3] += a0 * bq.w;
            acc[1][0] += a1 * bq.x; acc[1][1] += a1 * bq.y; acc[1][2] += a1 * bq.z; acc[1][3] += a1 * bq.w;
            acc[2][0] += a2 * bq.x; acc[2][1] += a2 * bq.y; acc[2][2] += a2 * bq.z; acc[2][3] += a2 * bq.w;
            acc[3][0] += a3 * bq.x; acc[3][1] += a3 * bq.y; acc[3][2] += a3 * bq.z; acc[3][3] += a3 * bq.w;
        }
#pragma unroll
        for (int ii = 0; ii < 4; ++ii)
            *(float4*)&T2[(i0 + ii) * TS + j0] = make_float4(acc[ii][0], acc[ii][1], acc[ii][2], acc[ii][3]);
    }
    if (t < 64) {
        float acc = 0.f;
#pragma unroll 8
        for (int i = 0; i < 64; ++i) acc += bw1[i] * A[i * 64 + t];
        bw2[t] = acc;
    }
    __syncthreads();
    {   // M = T2 @ B2 (64x16)
        int i = t >> 2, j0m = (t & 3) * 4;
        float4 acc = {0.f, 0.f, 0.f, 0.f};
#pragma unroll 8
        for (int k = 0; k < 64; ++k) {
            float a = T2[i * TS + k];
            float4 bq = *(const float4*)&B2[k * 16 + j0m];
            acc.x += a * bq.x; acc.y += a * bq.y; acc.z += a * bq.z; acc.w += a * bq.w;
        }
        *(float4*)&M[i * 16 + j0m] = acc;
    }
    if (t < 16) {
        float a3 = 0.f, a2 = 0.f, a1 = 0.f;
#pragma unroll 8
        for (int i = 0; i < 64; ++i) {
            float w = B2[i * 16 + t];
            a3 += bw2[i] * w;
            a2 += bw1[i] * w;
            a1 += bv[i] * w;
        }
        cvecs[t] = a3;
        cvecs[16 + t] = a2;
        cvecs[32 + t] = a1;
        cvecs[48 + t] = loadF(b2, t, bf);
    }
}

// ---------------- z0 = dinv * (x @ M) ----------------
__global__ void k_xm(const void* x, const float* M, const float* dinv, float* z0,
                     int n, const int* flags) {
    __shared__ float Ms[64 * 16];
    __shared__ float xs[16 * 64];
    int bf = flags[0];
    int t = threadIdx.x;   // 256
    ((float4*)Ms)[t] = ((const float4*)M)[t];
    int base = blockIdx.x * 16;
    if (!bf) {
        int row = base + (t >> 4);
        float4 v = make_float4(0.f, 0.f, 0.f, 0.f);
        if (row < n) v = ((const float4*)x)[base * 16 + t];
        ((float4*)xs)[t] = v;
    } else {
        for (int k = t; k < 1024; k += 256) {
            int r = k >> 6, cc = k & 63;
            int row = base + r;
            xs[k] = (row < n) ? bf2f(((const unsigned short*)x)[row * 64 + cc]) : 0.f;
        }
    }
    __syncthreads();
    int r = t >> 4, c = t & 15;
    int row = base + r;
    if (row < n) {
        float acc = 0.f;
#pragma unroll
        for (int k = 0; k < 64; ++k) acc += xs[r * 64 + k] * Ms[k * 16 + c];
        z0[row * 16 + c] = dinv[row] * acc;   // z-space
    }
}

// ---------------- propagation via LDS accumulate (push within bucket) ----------
// zacc[v] = sum_{edges (s->v)} z[s]; out = a*(zacc + z[v]) + b*cvec
__global__ void k_bprop(const float* zin, void* yout, const int2* bins,
                        const int* bcnt, int cap, int rsh, const float* dinv,
                        const float* cvec, int n, int is_final, const int* flags) {
    extern __shared__ float zacc[];        // R*16 floats
    const int R = 1 << rsh;
    const int b = blockIdx.x, t = threadIdx.x, nt = blockDim.x;
    const int bf = flags[0];
    for (int i = t; i < R * 4; i += nt) ((float4*)zacc)[i] = make_float4(0.f, 0.f, 0.f, 0.f);
    __syncthreads();
    int cnt = bcnt[b]; if (cnt > cap) cnt = cap;
    const int2* eb = bins + (size_t)b * cap;
    const int q = t & 3;
    const int mask = R - 1;
    for (int e = (t >> 2); e < cnt; e += (nt >> 2)) {
        int2 sd = eb[e];
        float4 zv = *(const float4*)&zin[(size_t)sd.x * 16 + q * 4];
        float* dst = &zacc[((sd.y & mask) << 4) + q * 4];
        atomicAdd(dst + 0, zv.x);
        atomicAdd(dst + 1, zv.y);
        atomicAdd(dst + 2, zv.z);
        atomicAdd(dst + 3, zv.w);
    }
    __syncthreads();
    const int v0 = b << rsh;
    for (int i = t; i < R * 4; i += nt) {
        int r = i >> 2, qq = i & 3;
        int v = v0 + r;
        if (v >= n) continue;
        float4 az = ((const float4*)zacc)[i];
        float4 self = *(const float4*)&zin[(size_t)v * 16 + qq * 4];
        float dv = dinv[v];
        float a  = is_final ? dv : dv * dv;
        float bb = is_final ? 1.0f : dv;
        float4 cv = *(const float4*)&cvec[qq * 4];
        float4 val;
        val.x = a * (az.x + self.x) + bb * cv.x;
        val.y = a * (az.y + self.y) + bb * cv.y;
        val.z = a * (az.z + self.z) + bb * cv.z;
        val.w = a * (az.w + self.w) + bb * cv.w;
        int o = v * 16 + qq * 4;
        if (is_final && bf) {
            ushort4 ov;
            ov.x = f2bf(val.x); ov.y = f2bf(val.y); ov.z = f2bf(val.z); ov.w = f2bf(val.w);
            *(ushort4*)&((unsigned short*)yout)[o] = ov;
        } else {
            *(float4*)&((float*)yout)[o] = val;
        }
    }
}

// ---------------- launch ----------------
extern "C" void kernel_launch(void* const* d_in, const int* in_sizes, int n_in,
                              void* d_out, int out_size, void* d_ws, size_t ws_size,
                              hipStream_t stream) {
    const void* x  = d_in[0];
    const void* W1 = d_in[1];
    const void* b1 = d_in[2];
    const void* W2 = d_in[3];
    const void* b2 = d_in[4];
    const void* ei = d_in[5];

    const int n = in_sizes[0] / 64;       // 100000
    const int E = in_sizes[5] / 2;        // 1000000

    // bucket geometry: R = 128 nodes/bucket (B <= 1024 for LDS histograms)
    int rsh = 7;
    while (((n + (1 << rsh) - 1) >> rsh) > 1024) ++rsh;
    const int B = (n + (1 << rsh) - 1) >> rsh;       // 782
    const int avg = E / B;
    int cap = avg + avg / 4 + 128;                    // mean + ~7 sigma slack
    cap = (cap + 31) & ~31;

    char* base = (char*)d_ws;
    size_t off = 0;
    auto carve = [&](size_t bytes) -> void* {
        void* r = base + off;
        off = (off + bytes + 255) & ~(size_t)255;
        return r;
    };
    int*   flags  = (int*)carve(8);
    int*   bcnt   = (int*)carve((size_t)B * 4);
    float* dinv   = (float*)carve((size_t)n * 4);
    int2*  bins   = (int2*)carve((size_t)B * cap * 8);
    float* Mm     = (float*)carve(1024 * 4);
    float* cvecs  = (float*)carve(64 * 4);
    float* z0     = (float*)carve((size_t)n * 16 * 4);
    float* z1     = (float*)carve((size_t)n * 16 * 4);
    (void)ws_size; (void)n_in; (void)out_size;

    hipMemsetAsync(bcnt, 0, (size_t)B * 4, stream);
    k_detect<<<1, 64, 0, stream>>>(x, ei, flags);
    k_bin<<<80, 512, (size_t)2 * B * 4, stream>>>(ei, E, rsh, B, cap, bins, bcnt, flags);
    k_bdeg<<<B, 256, (size_t)(1 << rsh) * 4, stream>>>(bins, bcnt, cap, rsh, n, dinv);
    k_consts<<<1, 256, 0, stream>>>(W1, b1, W2, b2, Mm, cvecs, flags);
    k_xm<<<(n + 15) / 16, 256, 0, stream>>>(x, Mm, dinv, z0, n, flags);

    const size_t plds = (size_t)(1 << rsh) * 16 * 4;   // 8 KB
    // z1 = P z0 + .. ; z0 = P z1 + .. ; z1 = P z0 + .. ; out = final(P z1)
    k_bprop<<<B, 256, plds, stream>>>(z0, z1, bins, bcnt, cap, rsh, dinv, cvecs + 0,  n, 0, flags);
    k_bprop<<<B, 256, plds, stream>>>(z1, z0, bins, bcnt, cap, rsh, dinv, cvecs + 16, n, 0, flags);
    k_bprop<<<B, 256, plds, stream>>>(z0, z1, bins, bcnt, cap, rsh, dinv, cvecs + 32, n, 0, flags);
    k_bprop<<<B, 256, plds, stream>>>(z1, d_out, bins, bcnt, cap, rsh, dinv, cvecs + 48, n, 1, flags);
}

// Round 5
// 152.783 us; speedup vs baseline: 3.3084x; 3.3084x over previous
//
#include <hip/hip_runtime.h>
#include <hip/hip_bf16.h>
#include <stdint.h>

// ---------------- helpers ----------------
__device__ __forceinline__ float bf2f(unsigned short u) {
    unsigned int x = ((unsigned int)u) << 16;
    return __uint_as_float(x);
}
__device__ __forceinline__ unsigned short f2bf(float f) {
    unsigned int x = __float_as_uint(f);
    unsigned int lsb = (x >> 16) & 1u;
    x += 0x7fffu + lsb;           // round-to-nearest-even
    return (unsigned short)(x >> 16);
}
__device__ __forceinline__ float loadF(const void* p, int i, int isbf) {
    return isbf ? bf2f(((const unsigned short*)p)[i]) : ((const float*)p)[i];
}

// ---------------- dtype detection (64-lane parallel) ----------------
// flags[0] = floats are bf16 (1) or f32 (0)
// flags[1] = edge_index is int64 (1) or int32 (0)
__global__ void k_detect(const void* x, const void* eidx, int* flags) {
    int l = threadIdx.x;   // 64 threads
    const unsigned short* u = (const unsigned short*)x;
    float a = fabsf(bf2f(u[2 * l]));
    bool ok = (a == 0.0f) || (a > 1e-30f && a < 1e4f);
    unsigned long long mbf = __ballot(ok);
    const int* ip = (const int*)eidx;
    unsigned long long mi64 = __ballot(ip[2 * l + 1] == 0);
    if (l == 0) {
        flags[0] = (mbf  == ~0ULL) ? 1 : 0;
        flags[1] = (mi64 == ~0ULL) ? 1 : 0;
    }
}

// ---------------- edge binning by dst range ----------------
// Bucket = dst >> rsh (R=128 nodes). Packed word = (src << rsh) | (dst & R-1).
// Per-block LDS histogram -> one global atomic per (block,bucket) ->
// contiguous segment writes.
__global__ void k_bin(const void* eidx, int E, int rsh, int B, int cap,
                      unsigned int* bins, int* bcnt, const int* flags) {
    extern __shared__ int sh[];            // 2*B ints
    int* hist   = sh;
    int* base_s = sh + B;
    const int i64 = flags[1];
    const int t = threadIdx.x, nt = blockDim.x;
    const long long i0 = (long long)blockIdx.x * E / gridDim.x;
    const long long i1 = (long long)(blockIdx.x + 1) * E / gridDim.x;
    const long long* e64 = (const long long*)eidx;
    const int* e32 = (const int*)eidx;
    const int mask = (1 << rsh) - 1;

    for (int b = t; b < B; b += nt) hist[b] = 0;
    __syncthreads();
    // pass 1: count
    for (long long i = i0 + t; i < i1; i += nt) {
        int d = i64 ? (int)e64[E + i] : e32[E + i];
        atomicAdd(&hist[d >> rsh], 1);
    }
    __syncthreads();
    // reserve segments
    for (int b = t; b < B; b += nt) {
        int c = hist[b];
        base_s[b] = c ? atomicAdd(&bcnt[b], c) : 0;
        hist[b] = 0;
    }
    __syncthreads();
    // pass 2: scatter (re-reads are L2-hot)
    for (long long i = i0 + t; i < i1; i += nt) {
        int d, s;
        if (i64) { d = (int)e64[E + i]; s = (int)e64[i]; }
        else     { d = e32[E + i];     s = e32[i]; }
        int b = d >> rsh;
        int pos = base_s[b] + atomicAdd(&hist[b], 1);
        if (pos >= cap) pos = cap - 1;     // paranoia guard
        bins[(size_t)b * cap + pos] = ((unsigned int)s << rsh) | (unsigned int)(d & mask);
    }
}

// ---------------- per-bucket CSR build: colb (dst-grouped src), rstart/rlen/dinv --
__global__ void k_csr(const unsigned int* bins, const int* bcnt, int cap, int rsh,
                      int n, int* colb, int* rstart, int* rlen, float* dinv) {
    __shared__ int dh[128], db[128], ch[128];
    const int R = 1 << rsh;                // 128
    const int b = blockIdx.x, t = threadIdx.x, nt = blockDim.x;
    const int mask = R - 1;
    for (int r = t; r < R; r += nt) { dh[r] = 0; ch[r] = 0; }
    __syncthreads();
    int cnt = bcnt[b]; if (cnt > cap) cnt = cap;
    const unsigned int* eb = bins + (size_t)b * cap;
    // histogram of dst-lo
    for (int e = t; e < cnt; e += nt)
        atomicAdd(&dh[eb[e] & mask], 1);
    __syncthreads();
    // inclusive scan of dh into db (Hillis-Steele over 128)
    if (t < R) db[t] = dh[t];
    __syncthreads();
    for (int off = 1; off < R; off <<= 1) {
        int add = 0;
        if (t < R && t >= off) add = db[t - off];
        __syncthreads();
        if (t < R) db[t] += add;
        __syncthreads();
    }
    // per-node outputs
    const int v0 = b << rsh;
    const int gbase = b * cap;
    if (t < R) {
        int v = v0 + t;
        if (v < n) {
            int len = dh[t];
            rstart[v] = gbase + db[t] - len;   // exclusive base
            rlen[v]   = len;
            dinv[v]   = rsqrtf((float)(len + 1));   // +1 self loop
        }
    }
    __syncthreads();
    // scatter src grouped by dst
    for (int e = t; e < cnt; e += nt) {
        unsigned int w = eb[e];
        int r = w & mask;
        int pos = (db[r] - dh[r]) + atomicAdd(&ch[r], 1);
        colb[gbase + pos] = (int)(w >> rsh);
    }
}

// ---------------- consts: M = W1^3 W2 ; cvecs = {g3,g2,g1,b2} ----------------
#define TS 68
__global__ void k_consts(const void* W1, const void* b1, const void* W2, const void* b2,
                         float* M, float* cvecs, const int* flags) {
    __shared__ float A[64 * 64];
    __shared__ float T1[64 * TS];
    __shared__ float T2[64 * TS];
    __shared__ float B2[64 * 16];
    __shared__ float bv[64], bw1[64], bw2[64];
    int bf = flags[0];
    int t = threadIdx.x;   // 256 threads
    for (int i = t; i < 4096; i += 256) A[i] = loadF(W1, i, bf);
    for (int i = t; i < 1024; i += 256) B2[i] = loadF(W2, i, bf);
    if (t < 64) bv[t] = loadF(b1, t, bf);
    __syncthreads();

    const int i0 = (t >> 4) * 4;
    const int j0 = (t & 15) * 4;
    {   // T1 = A @ A
        float acc[4][4] = {};
#pragma unroll 8
        for (int k = 0; k < 64; ++k) {
            float a0 = A[(i0 + 0) * 64 + k];
            float a1 = A[(i0 + 1) * 64 + k];
            float a2 = A[(i0 + 2) * 64 + k];
            float a3 = A[(i0 + 3) * 64 + k];
            float4 bq = *(const float4*)&A[k * 64 + j0];
            acc[0][0] += a0 * bq.x; acc[0][1] += a0 * bq.y; acc[0][2] += a0 * bq.z; acc[0][3] += a0 * bq.w;
            acc[1][0] += a1 * bq.x; acc[1][1] += a1 * bq.y; acc[1][2] += a1 * bq.z; acc[1][3] += a1 * bq.w;
            acc[2][0] += a2 * bq.x; acc[2][1] += a2 * bq.y; acc[2][2] += a2 * bq.z; acc[2][3] += a2 * bq.w;
            acc[3][0] += a3 * bq.x; acc[3][1] += a3 * bq.y; acc[3][2] += a3 * bq.z; acc[3][3] += a3 * bq.w;
        }
#pragma unroll
        for (int ii = 0; ii < 4; ++ii)
            *(float4*)&T1[(i0 + ii) * TS + j0] = make_float4(acc[ii][0], acc[ii][1], acc[ii][2], acc[ii][3]);
    }
    if (t < 64) {
        float acc = 0.f;
#pragma unroll 8
        for (int i = 0; i < 64; ++i) acc += bv[i] * A[i * 64 + t];
        bw1[t] = acc;
    }
    __syncthreads();
    {   // T2 = T1 @ A
        float acc[4][4] = {};
#pragma unroll 8
        for (int k = 0; k < 64; ++k) {
            float a0 = T1[(i0 + 0) * TS + k];
            float a1 = T1[(i0 + 1) * TS + k];
            float a2 = T1[(i0 + 2) * TS + k];
            float a3 = T1[(i0 + 3) * TS + k];
            float4 bq = *(const float4*)&A[k * 64 + j0];
            acc[0][0] += a0 * bq.x; acc[0][1] += a0 * bq.y; acc[0][2] += a0 * bq.z; acc[0][3] += a0 * bq.w;
            acc[1][0] += a1 * bq.x; acc[1][1] += a1 * bq.y; acc[1][2] += a1 * bq.z; acc[1][3] += a1 * bq.w;
            acc[2][0] += a2 * bq.x; acc[2][1] += a2 * bq.y; acc[2][2] += a2 * bq.z; acc[2][3] += a2 * bq.w;
            acc[3][0] += a3 * bq.x; acc[3][1] += a3 * bq.y; acc[3][2] += a3 * bq.z; acc[3][3] += a3 * bq.w;
        }
#pragma unroll
        for (int ii = 0; ii < 4; ++ii)
            *(float4*)&T2[(i0 + ii) * TS + j0] = make_float4(acc[ii][0], acc[ii][1], acc[ii][2], acc[ii][3]);
    }
    if (t < 64) {
        float acc = 0.f;
#pragma unroll 8
        for (int i = 0; i < 64; ++i) acc += bw1[i] * A[i * 64 + t];
        bw2[t] = acc;
    }
    __syncthreads();
    {   // M = T2 @ B2 (64x16)
        int i = t >> 2, j0m = (t & 3) * 4;
        float4 acc = {0.f, 0.f, 0.f, 0.f};
#pragma unroll 8
        for (int k = 0; k < 64; ++k) {
            float a = T2[i * TS + k];
            float4 bq = *(const float4*)&B2[k * 16 + j0m];
            acc.x += a * bq.x; acc.y += a * bq.y; acc.z += a * bq.z; acc.w += a * bq.w;
        }
        *(float4*)&M[i * 16 + j0m] = acc;
    }
    if (t < 16) {
        float a3 = 0.f, a2 = 0.f, a1 = 0.f;
#pragma unroll 8
        for (int i = 0; i < 64; ++i) {
            float w = B2[i * 16 + t];
            a3 += bw2[i] * w;
            a2 += bw1[i] * w;
            a1 += bv[i] * w;
        }
        cvecs[t] = a3;
        cvecs[16 + t] = a2;
        cvecs[32 + t] = a1;
        cvecs[48 + t] = loadF(b2, t, bf);
    }
}

// ---------------- z0 = dinv * (x @ M) ----------------
__global__ void k_xm(const void* x, const float* M, const float* dinv, float* z0,
                     int n, const int* flags) {
    __shared__ float Ms[64 * 16];
    __shared__ float xs[16 * 64];
    int bf = flags[0];
    int t = threadIdx.x;   // 256
    ((float4*)Ms)[t] = ((const float4*)M)[t];
    int base = blockIdx.x * 16;
    if (!bf) {
        int row = base + (t >> 4);
        float4 v = make_float4(0.f, 0.f, 0.f, 0.f);
        if (row < n) v = ((const float4*)x)[base * 16 + t];
        ((float4*)xs)[t] = v;
    } else {
        for (int k = t; k < 1024; k += 256) {
            int r = k >> 6, cc = k & 63;
            int row = base + r;
            xs[k] = (row < n) ? bf2f(((const unsigned short*)x)[row * 64 + cc]) : 0.f;
        }
    }
    __syncthreads();
    int r = t >> 4, c = t & 15;
    int row = base + r;
    if (row < n) {
        float acc = 0.f;
#pragma unroll
        for (int k = 0; k < 64; ++k) acc += xs[r * 64 + k] * Ms[k * 16 + c];
        z0[row * 16 + c] = dinv[row] * acc;   // z-space
    }
}

// ---------------- pull propagation in z-space (4 lanes per node, float4) -------
// sum = z[v] + sum_{s in N(v)} z[s]
// non-final: zout = dinv^2*sum + dinv*cvec ; final: yout = dinv*sum + cvec
__global__ void k_prop(const float* zin, void* yout, const int* rstart, const int* rlen,
                       const int* colb, const float* dinv, const float* cvec,
                       int n, int is_final, const int* flags) {
    int tid = blockIdx.x * blockDim.x + threadIdx.x;
    int v = tid >> 2, q = tid & 3;
    if (v >= n) return;
    int beg = rstart[v], len = rlen[v];
    float4 acc = *(const float4*)&zin[(size_t)v * 16 + q * 4];   // self-loop
    for (int j = beg; j < beg + len; ++j) {
        int ci = colb[j];
        float4 zv = *(const float4*)&zin[(size_t)ci * 16 + q * 4];
        acc.x += zv.x; acc.y += zv.y; acc.z += zv.z; acc.w += zv.w;
    }
    float dv = dinv[v];
    float a = is_final ? dv : dv * dv;
    float b = is_final ? 1.0f : dv;
    float4 cv = *(const float4*)&cvec[q * 4];
    float4 val;
    val.x = a * acc.x + b * cv.x;
    val.y = a * acc.y + b * cv.y;
    val.z = a * acc.z + b * cv.z;
    val.w = a * acc.w + b * cv.w;
    int o = v * 16 + q * 4;
    if (is_final && flags[0]) {
        ushort4 ov;
        ov.x = f2bf(val.x); ov.y = f2bf(val.y); ov.z = f2bf(val.z); ov.w = f2bf(val.w);
        *(ushort4*)&((unsigned short*)yout)[o] = ov;
    } else {
        *(float4*)&((float*)yout)[o] = val;
    }
}

// ---------------- launch ----------------
extern "C" void kernel_launch(void* const* d_in, const int* in_sizes, int n_in,
                              void* d_out, int out_size, void* d_ws, size_t ws_size,
                              hipStream_t stream) {
    const void* x  = d_in[0];
    const void* W1 = d_in[1];
    const void* b1 = d_in[2];
    const void* W2 = d_in[3];
    const void* b2 = d_in[4];
    const void* ei = d_in[5];

    const int n = in_sizes[0] / 64;       // 100000
    const int E = in_sizes[5] / 2;        // 1000000

    // bucket geometry: R = 128 nodes/bucket
    const int rsh = 7;
    const int B = (n + (1 << rsh) - 1) >> rsh;       // 782
    const int avg = E / B;
    int cap = avg + avg / 4 + 128;                    // mean + ~12 sigma slack
    cap = (cap + 31) & ~31;

    char* base = (char*)d_ws;
    size_t off = 0;
    auto carve = [&](size_t bytes) -> void* {
        void* r = base + off;
        off = (off + bytes + 255) & ~(size_t)255;
        return r;
    };
    int*          flags  = (int*)carve(8);
    int*          bcnt   = (int*)carve((size_t)B * 4);
    float*        dinv   = (float*)carve((size_t)n * 4);
    unsigned int* bins   = (unsigned int*)carve((size_t)B * cap * 4);
    int*          colb   = (int*)carve((size_t)B * cap * 4);
    int*          rstart = (int*)carve((size_t)n * 4);
    int*          rlen   = (int*)carve((size_t)n * 4);
    float*        Mm     = (float*)carve(1024 * 4);
    float*        cvecs  = (float*)carve(64 * 4);
    float*        z0     = (float*)carve((size_t)n * 16 * 4);
    float*        z1     = (float*)carve((size_t)n * 16 * 4);
    (void)ws_size; (void)n_in; (void)out_size;

    hipMemsetAsync(bcnt, 0, (size_t)B * 4, stream);
    k_detect<<<1, 64, 0, stream>>>(x, ei, flags);
    k_bin<<<80, 512, (size_t)2 * B * 4, stream>>>(ei, E, rsh, B, cap, bins, bcnt, flags);
    k_csr<<<B, 256, 0, stream>>>(bins, bcnt, cap, rsh, n, colb, rstart, rlen, dinv);
    k_consts<<<1, 256, 0, stream>>>(W1, b1, W2, b2, Mm, cvecs, flags);
    k_xm<<<(n + 15) / 16, 256, 0, stream>>>(x, Mm, dinv, z0, n, flags);

    const int pgrid = (n * 4 + 255) / 256;
    // z1 = P z0 + .. ; z0 = P z1 + .. ; z1 = P z0 + .. ; out = final(P z1)
    k_prop<<<pgrid, 256, 0, stream>>>(z0, z1, rstart, rlen, colb, dinv, cvecs + 0,  n, 0, flags);
    k_prop<<<pgrid, 256, 0, stream>>>(z1, z0, rstart, rlen, colb, dinv, cvecs + 16, n, 0, flags);
    k_prop<<<pgrid, 256, 0, stream>>>(z0, z1, rstart, rlen, colb, dinv, cvecs + 32, n, 0, flags);
    k_prop<<<pgrid, 256, 0, stream>>>(z1, d_out, rstart, rlen, colb, dinv, cvecs + 48, n, 1, flags);
}